// Round 1
// baseline (1068.437 us; speedup 1.0000x reference)
//
#include <hip/hip_runtime.h>
#include <hip/hip_bf16.h>
#include <math.h>

#define H 512
#define NT 6

// edge GEMM tile
#define EBM 128
#define EBN 128
#define EBK 32
// gru GEMM tile
#define GBM 128
#define GBN 64
#define GBK 32

typedef short bf16x8 __attribute__((ext_vector_type(8)));
typedef float f32x4 __attribute__((ext_vector_type(4)));

__device__ __forceinline__ float sigmoidf_(float x) { return 1.0f / (1.0f + expf(-x)); }

__device__ __forceinline__ unsigned short f2bf(float f) {
    unsigned int u = __float_as_uint(f);
    u = (u + 0x7FFF + ((u >> 16) & 1)) >> 16;
    return (unsigned short)u;
}

// async global->LDS, 16B per lane. LDS dest must be lane-linear (wave base + lane*16);
// global src may be per-lane (gather ok).
__device__ __forceinline__ void glds16(const void* g, void* l) {
    __builtin_amdgcn_global_load_lds((const __attribute__((address_space(1))) unsigned int*)g,
                                     (__attribute__((address_space(3))) unsigned int*)l,
                                     16, 0, 0);
}

// ---------------- edge-type counting sort (block-aggregated atomics) ----------------
// meta layout (ints): [0..7]=counts, [8..14]=paddedStart (NT+1 used), [16..23]=cursor
__global__ void hist_kernel(const int* __restrict__ etype, int E, int* __restrict__ meta) {
    __shared__ int lh[NT];
    if (threadIdx.x < NT) lh[threadIdx.x] = 0;
    __syncthreads();
    int i = blockIdx.x * blockDim.x + threadIdx.x;
    if (i < E) atomicAdd(&lh[etype[i]], 1);
    __syncthreads();
    if (threadIdx.x < NT) {
        int c = lh[threadIdx.x];
        if (c) atomicAdd(&meta[threadIdx.x], c);
    }
}

__global__ void prefix_kernel(int* __restrict__ meta) {
    if (threadIdx.x == 0 && blockIdx.x == 0) {
        int acc = 0;
        for (int t = 0; t < NT; ++t) {
            meta[8 + t]  = acc;
            meta[16 + t] = acc;
            acc += ((meta[t] + EBM - 1) / EBM) * EBM;
        }
        meta[8 + NT] = acc;
    }
}

__global__ void scatter_perm_kernel(const int* __restrict__ etype, int E,
                                    int* __restrict__ meta, int* __restrict__ perm) {
    __shared__ int lcount[NT];
    __shared__ int lbase[NT];
    const int tid = threadIdx.x;
    if (tid < NT) lcount[tid] = 0;
    __syncthreads();
    int i = blockIdx.x * blockDim.x + tid;
    int t = 0, rank = 0;
    if (i < E) {
        t = etype[i];
        rank = atomicAdd(&lcount[t], 1);      // intra-block rank (LDS)
    }
    __syncthreads();
    if (tid < NT) {
        int c = lcount[tid];
        lbase[tid] = c ? atomicAdd(&meta[16 + tid], c) : 0;  // reserve block span
    }
    __syncthreads();
    if (i < E) perm[lbase[t] + rank] = i;
}

// ---------------- fp32 -> bf16 elementwise (x4) ----------------
__global__ void conv_bf16_kernel(const float* __restrict__ in, unsigned short* __restrict__ out, int n4) {
    int i = blockIdx.x * blockDim.x + threadIdx.x;
    if (i < n4) {
        float4 v = ((const float4*)in)[i];
        ushort4 o;
        o.x = f2bf(v.x); o.y = f2bf(v.y); o.z = f2bf(v.z); o.w = f2bf(v.w);
        ((ushort4*)out)[i] = o;
    }
}

// ---------------- GRU weights -> bf16, transposed B^T[n][k] ----------------
__global__ void conv_gru_w_kernel(const float* __restrict__ Wir, const float* __restrict__ Wiz,
                                  const float* __restrict__ Win, const float* __restrict__ Whr,
                                  const float* __restrict__ Whz, const float* __restrict__ Whn,
                                  unsigned short* __restrict__ Brt, unsigned short* __restrict__ Bzt,
                                  unsigned short* __restrict__ Bnit, unsigned short* __restrict__ Bnht) {
    int idx = blockIdx.x * blockDim.x + threadIdx.x;
    if (idx >= 512 * 1024) return;
    int n = idx >> 10;
    int k = idx & 1023;
    int kk = k & 511;
    const float* wr = (k < 512) ? Wir : Whr;
    const float* wz = (k < 512) ? Wiz : Whz;
    Brt[idx] = f2bf(wr[kk * H + n]);
    Bzt[idx] = f2bf(wz[kk * H + n]);
    if (k < 512) Bnit[n * H + k]  = f2bf(Win[k * H + n]);
    else         Bnht[n * H + kk] = f2bf(Whn[kk * H + n]);
}

// W_edge (512 x 3072) -> WeT[3072][512] bf16
__global__ void conv_edge_w_kernel(const float* __restrict__ W_edge, unsigned short* __restrict__ WeT) {
    int idx = blockIdx.x * blockDim.x + threadIdx.x;
    if (idx >= 3072 * 512) return;
    int n = idx >> 9;
    int k = idx & 511;
    WeT[idx] = f2bf(W_edge[(size_t)k * (NT * H) + n]);
}

// ---------------- edge message GEMM (MFMA, 128x128, global_load_lds) + scatter-add ----------------
__global__ __launch_bounds__(256)
void edge_msg_mfma(const unsigned short* __restrict__ emb_bf,
                   const int* __restrict__ src_idx,
                   const int* __restrict__ dst_idx,
                   const float* __restrict__ b_edge,
                   const unsigned short* __restrict__ WeT,
                   const int* __restrict__ meta,
                   const int* __restrict__ perm,
                   float* __restrict__ proposed)
{
    __shared__ short As[EBM * EBK];   // [128 rows][32 k], linear (required by global_load_lds)
    __shared__ short Bs[EBN * EBK];   // [128 cols][32 k], linear
    __shared__ int ls_src[EBM];
    __shared__ int ls_dst[EBM];

    const int rowBase = blockIdx.y * EBM;
    if (rowBase >= meta[8 + NT]) return;
    int t = 0;
    while (rowBase >= meta[8 + t + 1]) ++t;

    const int colBase = blockIdx.x * EBN;
    const int tid = threadIdx.x;

    if (tid < EBM) {
        int e = perm[rowBase + tid];
        int s = 0, d = -1;                       // padded rows read row 0 (results discarded)
        if (e >= 0) { s = src_idx[e] * H; d = dst_idx[e] * H; }
        ls_src[tid] = s;
        ls_dst[tid] = d;
    }
    __syncthreads();

    const int lane = tid & 63;
    const int wave = tid >> 6;
    const int wm = (wave >> 1) * 64;             // wave tile 64x64 of the 128x128 block
    const int wn = (wave & 1) * 64;
    const int q = lane >> 4;
    const int r = lane & 15;

    const int rA   = tid >> 2;                   // 0..63: staging row within half-tile
    const int slot = (tid & 3) * 8;              // 0/8/16/24 shorts (16B chunk)

    const int s0 = ls_src[rA];
    const int s1 = ls_src[64 + rA];
    const size_t b0 = ((size_t)(t * H + colBase + rA)) * H + slot;
    const size_t b1 = ((size_t)(t * H + colBase + 64 + rA)) * H + slot;

    f32x4 acc[4][4];
    #pragma unroll
    for (int i = 0; i < 4; ++i)
        #pragma unroll
        for (int j = 0; j < 4; ++j) acc[i][j] = (f32x4){0.f, 0.f, 0.f, 0.f};

    for (int k0 = 0; k0 < H; k0 += EBK) {
        glds16(emb_bf + (size_t)s0 + k0 + slot, &As[tid * 8]);
        glds16(emb_bf + (size_t)s1 + k0 + slot, &As[(256 + tid) * 8]);
        glds16(WeT + b0 + k0, &Bs[tid * 8]);
        glds16(WeT + b1 + k0, &Bs[(256 + tid) * 8]);
        __syncthreads();                          // drains vmcnt -> LDS tiles ready

        bf16x8 a[4];
        #pragma unroll
        for (int i = 0; i < 4; ++i)
            a[i] = *(const bf16x8*)&As[(wm + i * 16 + r) * EBK + q * 8];
        #pragma unroll
        for (int j = 0; j < 4; ++j) {
            bf16x8 b = *(const bf16x8*)&Bs[(wn + j * 16 + r) * EBK + q * 8];
            #pragma unroll
            for (int i = 0; i < 4; ++i)
                acc[i][j] = __builtin_amdgcn_mfma_f32_16x16x32_bf16(a[i], b, acc[i][j], 0, 0, 0);
        }
        __syncthreads();
    }

    int cols[4];
    float bias[4];
    #pragma unroll
    for (int j = 0; j < 4; ++j) {
        cols[j] = colBase + wn + j * 16 + r;
        bias[j] = b_edge[t * H + cols[j]];
    }
    #pragma unroll
    for (int i = 0; i < 4; ++i) {
        #pragma unroll
        for (int reg = 0; reg < 4; ++reg) {
            int row = wm + i * 16 + q * 4 + reg;
            int d = ls_dst[row];
            if (d < 0) continue;
            #pragma unroll
            for (int j = 0; j < 4; ++j)
                atomicAdd(&proposed[(size_t)d + cols[j]], acc[i][j][reg] + bias[j]);
        }
    }
}

// ---------------- fused GRU (MFMA, 128x64, global_load_lds): A' = [P | H] over K=1024 ----------------
__global__ __launch_bounds__(256)
void gru_mfma(const unsigned short* __restrict__ prop_bf,
              const unsigned short* __restrict__ emb_bf,
              const float* __restrict__ emb_f32,
              const unsigned short* __restrict__ Brt,
              const unsigned short* __restrict__ Bzt,
              const unsigned short* __restrict__ Bnit,
              const unsigned short* __restrict__ Bnht,
              const float* __restrict__ bir, const float* __restrict__ biz,
              const float* __restrict__ bin, const float* __restrict__ bhn,
              float* __restrict__ out, int N)
{
    __shared__ short As[GBM * GBK];    // 8KB  [128 rows][32 k] linear
    __shared__ short Brs[GBN * GBK];   // 4KB  [64 cols][32 k] linear
    __shared__ short Bzs[GBN * GBK];
    __shared__ short Bns[GBN * GBK];

    // XCD-aware swizzle (T1): 8 col-blocks sharing an A row-panel land on one XCD.
    int wg = blockIdx.y * gridDim.x + blockIdx.x;
    const int nwg = gridDim.x * gridDim.y;
    if ((nwg & 7) == 0) {
        const int cpx = nwg >> 3;
        wg = (wg & 7) * cpx + (wg >> 3);
    }
    const int rowBase = (wg / gridDim.x) * GBM;
    const int colBase = (wg % gridDim.x) * GBN;

    const int tid = threadIdx.x;
    const int lane = tid & 63;
    const int wave = tid >> 6;
    const int wm = (wave >> 1) * 64;             // wave tile 64 rows x 32 cols
    const int wn = (wave & 1) * 32;
    const int q = lane >> 4;
    const int r = lane & 15;

    const int rA   = tid >> 2;                   // 0..63
    const int slot = (tid & 3) * 8;

    const size_t aOff0  = (size_t)(rowBase + rA) * H + slot;
    const size_t aOff1  = (size_t)(rowBase + 64 + rA) * H + slot;
    const size_t bOffRZ = (size_t)(colBase + rA) * 1024 + slot;
    const size_t bOffN  = (size_t)(colBase + rA) * 512 + slot;

    f32x4 accR[4][2], accZ[4][2], accNI[4][2], accNH[4][2];
    #pragma unroll
    for (int i = 0; i < 4; ++i)
        #pragma unroll
        for (int j = 0; j < 2; ++j) {
            accR[i][j] = (f32x4){0.f, 0.f, 0.f, 0.f};
            accZ[i][j] = accR[i][j];
            accNI[i][j] = accR[i][j];
            accNH[i][j] = accR[i][j];
        }

    // One K-step: stage A(128x32) + Br/Bz/Bn(64x32 each) via DMA, 2 barriers, 24 MFMA/wave.
    // ACCN is selected at compile time per half (avoids runtime-indexed acc -> scratch).
#define GRU_STEP(ASRC, BNSRC, ACCN, K0, KK)                                                          \
    {                                                                                                \
        glds16(ASRC + aOff0 + (KK), &As[tid * 8]);                                                   \
        glds16(ASRC + aOff1 + (KK), &As[(256 + tid) * 8]);                                           \
        glds16(Brt + bOffRZ + (K0), &Brs[tid * 8]);                                                  \
        glds16(Bzt + bOffRZ + (K0), &Bzs[tid * 8]);                                                  \
        glds16(BNSRC + bOffN + (KK), &Bns[tid * 8]);                                                 \
        __syncthreads();                                                                             \
        bf16x8 a[4];                                                                                 \
        _Pragma("unroll")                                                                            \
        for (int i = 0; i < 4; ++i)                                                                  \
            a[i] = *(const bf16x8*)&As[(wm + i * 16 + r) * GBK + q * 8];                             \
        _Pragma("unroll")                                                                            \
        for (int j = 0; j < 2; ++j) {                                                                \
            bf16x8 br = *(const bf16x8*)&Brs[(wn + j * 16 + r) * GBK + q * 8];                       \
            bf16x8 bz = *(const bf16x8*)&Bzs[(wn + j * 16 + r) * GBK + q * 8];                       \
            bf16x8 bn = *(const bf16x8*)&Bns[(wn + j * 16 + r) * GBK + q * 8];                       \
            _Pragma("unroll")                                                                        \
            for (int i = 0; i < 4; ++i) {                                                            \
                accR[i][j] = __builtin_amdgcn_mfma_f32_16x16x32_bf16(a[i], br, accR[i][j], 0, 0, 0); \
                accZ[i][j] = __builtin_amdgcn_mfma_f32_16x16x32_bf16(a[i], bz, accZ[i][j], 0, 0, 0); \
                ACCN[i][j] = __builtin_amdgcn_mfma_f32_16x16x32_bf16(a[i], bn, ACCN[i][j], 0, 0, 0); \
            }                                                                                        \
        }                                                                                            \
        __syncthreads();                                                                             \
    }

    for (int k0 = 0; k0 < 512; k0 += GBK)
        GRU_STEP(prop_bf, Bnit, accNI, k0, k0)
    for (int k0 = 512; k0 < 1024; k0 += GBK)
        GRU_STEP(emb_bf, Bnht, accNH, k0, k0 - 512)
#undef GRU_STEP

    #pragma unroll
    for (int j = 0; j < 2; ++j) {
        const int col = colBase + wn + j * 16 + r;
        const float vbir = bir[col], vbiz = biz[col], vbin = bin[col], vbhn = bhn[col];
        #pragma unroll
        for (int i = 0; i < 4; ++i) {
            #pragma unroll
            for (int reg = 0; reg < 4; ++reg) {
                const int row = rowBase + wm + i * 16 + q * 4 + reg;
                if (row >= N) continue;
                float rg = sigmoidf_(accR[i][j][reg] + vbir);
                float zg = sigmoidf_(accZ[i][j][reg] + vbiz);
                float ng = tanhf(accNI[i][j][reg] + vbin + rg * (accNH[i][j][reg] + vbhn));
                float h = emb_f32[(size_t)row * H + col];
                out[(size_t)row * H + col] = (1.0f - zg) * ng + zg * h;
            }
        }
    }
}

extern "C" void kernel_launch(void* const* d_in, const int* in_sizes, int n_in,
                              void* d_out, int out_size, void* d_ws, size_t ws_size,
                              hipStream_t stream) {
    const float* emb     = (const float*)d_in[0];
    const int*   src_idx = (const int*)d_in[1];
    const int*   dst_idx = (const int*)d_in[2];
    const int*   etype   = (const int*)d_in[3];
    const float* W_edge  = (const float*)d_in[6];
    const float* b_edge  = (const float*)d_in[7];
    const float* Wir = (const float*)d_in[8];
    const float* Wiz = (const float*)d_in[9];
    const float* Win = (const float*)d_in[10];
    const float* bir = (const float*)d_in[11];
    const float* biz = (const float*)d_in[12];
    const float* bin = (const float*)d_in[13];
    const float* Whr = (const float*)d_in[14];
    const float* Whz = (const float*)d_in[15];
    const float* Whn = (const float*)d_in[16];
    const float* bhn = (const float*)d_in[17];

    const int E = in_sizes[1];
    const int N = in_sizes[0] / H;
    const int NH = N * H;

    char* ws = (char*)d_ws;
    float*          proposed = (float*)ws;                       ws += (size_t)NH * 4;
    unsigned short* prop_bf  = (unsigned short*)ws;              ws += (size_t)NH * 2;
    unsigned short* emb_bf   = (unsigned short*)ws;              ws += (size_t)NH * 2;
    unsigned short* Brt      = (unsigned short*)ws;              ws += 512 * 1024 * 2;
    unsigned short* Bzt      = (unsigned short*)ws;              ws += 512 * 1024 * 2;
    unsigned short* Bnit     = (unsigned short*)ws;              ws += 512 * 512 * 2;
    unsigned short* Bnht     = (unsigned short*)ws;              ws += 512 * 512 * 2;
    unsigned short* WeT      = (unsigned short*)ws;              ws += 3072 * 512 * 2;
    int*            meta     = (int*)ws;                         ws += 32 * 4;
    int*            perm     = (int*)ws;
    const int maxRowTiles = (E + EBM - 1) / EBM + NT;

    hipMemsetAsync(proposed, 0, (size_t)NH * 4, stream);
    hipMemsetAsync(meta, 0, 32 * 4, stream);
    hipMemsetAsync(perm, 0xFF, (size_t)maxRowTiles * EBM * 4, stream);

    const int n4 = NH / 4;
    conv_bf16_kernel<<<(n4 + 255) / 256, 256, 0, stream>>>(emb, emb_bf, n4);
    conv_gru_w_kernel<<<(512 * 1024 + 255) / 256, 256, 0, stream>>>(
        Wir, Wiz, Win, Whr, Whz, Whn, Brt, Bzt, Bnit, Bnht);
    conv_edge_w_kernel<<<(3072 * 512 + 255) / 256, 256, 0, stream>>>(W_edge, WeT);

    hist_kernel<<<(E + 255) / 256, 256, 0, stream>>>(etype, E, meta);
    prefix_kernel<<<1, 64, 0, stream>>>(meta);
    scatter_perm_kernel<<<(E + 255) / 256, 256, 0, stream>>>(etype, E, meta, perm);

    dim3 egrid(H / EBN, maxRowTiles);
    edge_msg_mfma<<<egrid, 256, 0, stream>>>(emb_bf, src_idx, dst_idx, b_edge, WeT,
                                             meta, perm, proposed);

    conv_bf16_kernel<<<(n4 + 255) / 256, 256, 0, stream>>>(proposed, prop_bf, n4);

    dim3 ggrid(H / GBN, (N + GBM - 1) / GBM);
    gru_mfma<<<ggrid, 256, 0, stream>>>(prop_bf, emb_bf, emb, Brt, Bzt, Bnit, Bnht,
                                        bir, biz, bin, bhn, (float*)d_out, N);
}

// Round 2
// 877.694 us; speedup vs baseline: 1.2173x; 1.2173x over previous
//
#include <hip/hip_runtime.h>
#include <hip/hip_bf16.h>
#include <math.h>

#define H 512
#define NT 6

// edge GEMM tile
#define EBM 128
#define EBN 128
#define EBK 32
// gru GEMM tile
#define GBM 128
#define GBN 64
#define GBK 32

typedef short bf16x8 __attribute__((ext_vector_type(8)));
typedef float f32x4 __attribute__((ext_vector_type(4)));

__device__ __forceinline__ float sigmoidf_(float x) { return 1.0f / (1.0f + expf(-x)); }

__device__ __forceinline__ unsigned short f2bf(float f) {
    unsigned int u = __float_as_uint(f);
    u = (u + 0x7FFF + ((u >> 16) & 1)) >> 16;
    return (unsigned short)u;
}

// async global->LDS, 16B per lane. LDS dest must be lane-linear (wave base + lane*16);
// global src may be per-lane (gather ok).
__device__ __forceinline__ void glds16(const void* g, void* l) {
    __builtin_amdgcn_global_load_lds((const __attribute__((address_space(1))) unsigned int*)g,
                                     (__attribute__((address_space(3))) unsigned int*)l,
                                     16, 0, 0);
}

// ---------------- edge-type counting sort (block-aggregated atomics) ----------------
// meta layout (ints): [0..7]=counts, [8..14]=paddedStart (NT+1 used), [16..23]=cursor
__global__ void hist_kernel(const int* __restrict__ etype, int E, int* __restrict__ meta) {
    __shared__ int lh[NT];
    if (threadIdx.x < NT) lh[threadIdx.x] = 0;
    __syncthreads();
    int i = blockIdx.x * blockDim.x + threadIdx.x;
    if (i < E) atomicAdd(&lh[etype[i]], 1);
    __syncthreads();
    if (threadIdx.x < NT) {
        int c = lh[threadIdx.x];
        if (c) atomicAdd(&meta[threadIdx.x], c);
    }
}

__global__ void prefix_kernel(int* __restrict__ meta) {
    if (threadIdx.x == 0 && blockIdx.x == 0) {
        int acc = 0;
        for (int t = 0; t < NT; ++t) {
            meta[8 + t]  = acc;
            meta[16 + t] = acc;
            acc += ((meta[t] + EBM - 1) / EBM) * EBM;
        }
        meta[8 + NT] = acc;
    }
}

__global__ void scatter_perm_kernel(const int* __restrict__ etype, int E,
                                    int* __restrict__ meta, int* __restrict__ perm) {
    __shared__ int lcount[NT];
    __shared__ int lbase[NT];
    const int tid = threadIdx.x;
    if (tid < NT) lcount[tid] = 0;
    __syncthreads();
    int i = blockIdx.x * blockDim.x + tid;
    int t = 0, rank = 0;
    if (i < E) {
        t = etype[i];
        rank = atomicAdd(&lcount[t], 1);      // intra-block rank (LDS)
    }
    __syncthreads();
    if (tid < NT) {
        int c = lcount[tid];
        lbase[tid] = c ? atomicAdd(&meta[16 + tid], c) : 0;  // reserve block span
    }
    __syncthreads();
    if (i < E) perm[lbase[t] + rank] = i;
}

// ---------------- fp32 -> bf16 elementwise (x4) ----------------
__global__ void conv_bf16_kernel(const float* __restrict__ in, unsigned short* __restrict__ out, int n4) {
    int i = blockIdx.x * blockDim.x + threadIdx.x;
    if (i < n4) {
        float4 v = ((const float4*)in)[i];
        ushort4 o;
        o.x = f2bf(v.x); o.y = f2bf(v.y); o.z = f2bf(v.z); o.w = f2bf(v.w);
        ((ushort4*)out)[i] = o;
    }
}

// ---------------- GRU weights -> bf16, transposed B^T[n][k] ----------------
__global__ void conv_gru_w_kernel(const float* __restrict__ Wir, const float* __restrict__ Wiz,
                                  const float* __restrict__ Win, const float* __restrict__ Whr,
                                  const float* __restrict__ Whz, const float* __restrict__ Whn,
                                  unsigned short* __restrict__ Brt, unsigned short* __restrict__ Bzt,
                                  unsigned short* __restrict__ Bnit, unsigned short* __restrict__ Bnht) {
    int idx = blockIdx.x * blockDim.x + threadIdx.x;
    if (idx >= 512 * 1024) return;
    int n = idx >> 10;
    int k = idx & 1023;
    int kk = k & 511;
    const float* wr = (k < 512) ? Wir : Whr;
    const float* wz = (k < 512) ? Wiz : Whz;
    Brt[idx] = f2bf(wr[kk * H + n]);
    Bzt[idx] = f2bf(wz[kk * H + n]);
    if (k < 512) Bnit[n * H + k]  = f2bf(Win[k * H + n]);
    else         Bnht[n * H + kk] = f2bf(Whn[kk * H + n]);
}

// W_edge (512 x 3072) -> WeT[3072][512] bf16
__global__ void conv_edge_w_kernel(const float* __restrict__ W_edge, unsigned short* __restrict__ WeT) {
    int idx = blockIdx.x * blockDim.x + threadIdx.x;
    if (idx >= 3072 * 512) return;
    int n = idx >> 9;
    int k = idx & 511;
    WeT[idx] = f2bf(W_edge[(size_t)k * (NT * H) + n]);
}

// ---------------- edge message GEMM (MFMA, 128x128, 2-phase dbuf) + scatter-add ----------------
__global__ __launch_bounds__(256)
void edge_msg_mfma(const unsigned short* __restrict__ emb_bf,
                   const int* __restrict__ src_idx,
                   const int* __restrict__ dst_idx,
                   const float* __restrict__ b_edge,
                   const unsigned short* __restrict__ WeT,
                   const int* __restrict__ meta,
                   const int* __restrict__ perm,
                   float* __restrict__ proposed)
{
    __shared__ short As[2][EBM * EBK];   // 2 x 8KB, linear (required by global_load_lds)
    __shared__ short Bs[2][EBN * EBK];   // 2 x 8KB
    __shared__ int ls_src[EBM];
    __shared__ int ls_dst[EBM];

    const int rowBase = blockIdx.y * EBM;
    if (rowBase >= meta[8 + NT]) return;
    int t = 0;
    while (rowBase >= meta[8 + t + 1]) ++t;

    const int colBase = blockIdx.x * EBN;
    const int tid = threadIdx.x;

    if (tid < EBM) {
        int e = perm[rowBase + tid];
        int s = 0, d = -1;                       // padded rows read row 0 (results discarded)
        if (e >= 0) { s = src_idx[e] * H; d = dst_idx[e] * H; }
        ls_src[tid] = s;
        ls_dst[tid] = d;
    }
    __syncthreads();

    const int lane = tid & 63;
    const int wave = tid >> 6;
    const int wm = (wave >> 1) * 64;             // wave tile 64x64 of the 128x128 block
    const int wn = (wave & 1) * 64;
    const int q = lane >> 4;
    const int r = lane & 15;

    const int rA   = tid >> 2;                   // 0..63: staging row within half-tile
    const int slot = (tid & 3) * 8;              // 0/8/16/24 shorts (16B chunk)

    const int s0 = ls_src[rA];
    const int s1 = ls_src[64 + rA];
    const size_t b0 = ((size_t)(t * H + colBase + rA)) * H + slot;
    const size_t b1 = ((size_t)(t * H + colBase + 64 + rA)) * H + slot;

    f32x4 acc[4][4];
    #pragma unroll
    for (int i = 0; i < 4; ++i)
        #pragma unroll
        for (int j = 0; j < 4; ++j) acc[i][j] = (f32x4){0.f, 0.f, 0.f, 0.f};

// issue next K-tile's DMA (stays in flight across the compute phase)
#define ESTAGE(K0, B)                                                   \
    {                                                                   \
        glds16(emb_bf + (size_t)s0 + (K0) + slot, &As[B][tid * 8]);     \
        glds16(emb_bf + (size_t)s1 + (K0) + slot, &As[B][(256 + tid) * 8]); \
        glds16(WeT + b0 + (K0), &Bs[B][tid * 8]);                       \
        glds16(WeT + b1 + (K0), &Bs[B][(256 + tid) * 8]);               \
    }

    ESTAGE(0, 0);
    __syncthreads();                             // tile 0 landed
    int cur = 0;

    for (int k0 = 0; k0 < H; k0 += EBK) {
        if (k0 + EBK < H) ESTAGE(k0 + EBK, cur ^ 1);   // issue-early

        bf16x8 a[4];
        #pragma unroll
        for (int i = 0; i < 4; ++i)
            a[i] = *(const bf16x8*)&As[cur][(wm + i * 16 + r) * EBK + q * 8];
        #pragma unroll
        for (int j = 0; j < 4; ++j) {
            bf16x8 b = *(const bf16x8*)&Bs[cur][(wn + j * 16 + r) * EBK + q * 8];
            #pragma unroll
            for (int i = 0; i < 4; ++i)
                acc[i][j] = __builtin_amdgcn_mfma_f32_16x16x32_bf16(a[i], b, acc[i][j], 0, 0, 0);
        }
        __syncthreads();                         // drains vmcnt (t+1 ready) + read-done
        cur ^= 1;
    }
#undef ESTAGE

    int cols[4];
    float bias[4];
    #pragma unroll
    for (int j = 0; j < 4; ++j) {
        cols[j] = colBase + wn + j * 16 + r;
        bias[j] = b_edge[t * H + cols[j]];
    }
    #pragma unroll
    for (int i = 0; i < 4; ++i) {
        #pragma unroll
        for (int reg = 0; reg < 4; ++reg) {
            int row = wm + i * 16 + q * 4 + reg;
            int d = ls_dst[row];
            if (d < 0) continue;
            #pragma unroll
            for (int j = 0; j < 4; ++j)
                atomicAdd(&proposed[(size_t)d + cols[j]], acc[i][j][reg] + bias[j]);
        }
    }
}

// ---------------- fused GRU (MFMA, 128x64, 2-phase dbuf): A' = [P | H] over K=1024 ----------------
__global__ __launch_bounds__(256)
void gru_mfma(const unsigned short* __restrict__ prop_bf,
              const unsigned short* __restrict__ emb_bf,
              const float* __restrict__ emb_f32,
              const unsigned short* __restrict__ Brt,
              const unsigned short* __restrict__ Bzt,
              const unsigned short* __restrict__ Bnit,
              const unsigned short* __restrict__ Bnht,
              const float* __restrict__ bir, const float* __restrict__ biz,
              const float* __restrict__ bin, const float* __restrict__ bhn,
              float* __restrict__ out, int N)
{
    __shared__ short As[2][GBM * GBK];    // 2 x 8KB linear
    __shared__ short Brs[2][GBN * GBK];   // 2 x 4KB
    __shared__ short Bzs[2][GBN * GBK];
    __shared__ short Bns[2][GBN * GBK];   // total 40KB

    // XCD-aware swizzle (T1): contiguous logical-tile chunk per XCD.
    int wg = blockIdx.y * gridDim.x + blockIdx.x;
    const int nwg = gridDim.x * gridDim.y;
    if ((nwg & 7) == 0) {
        const int cpx = nwg >> 3;
        wg = (wg & 7) * cpx + (wg >> 3);
    }
    const int rowBase = (wg / gridDim.x) * GBM;
    const int colBase = (wg % gridDim.x) * GBN;

    const int tid = threadIdx.x;
    const int lane = tid & 63;
    const int wave = tid >> 6;
    const int wm = (wave >> 1) * 64;             // wave tile 64 rows x 32 cols
    const int wn = (wave & 1) * 32;
    const int q = lane >> 4;
    const int r = lane & 15;

    const int rA   = tid >> 2;                   // 0..63
    const int slot = (tid & 3) * 8;

    const size_t aOff0  = (size_t)(rowBase + rA) * H + slot;
    const size_t aOff1  = (size_t)(rowBase + 64 + rA) * H + slot;
    const size_t bOffRZ = (size_t)(colBase + rA) * 1024 + slot;
    const size_t bOffN  = (size_t)(colBase + rA) * 512 + slot;

    f32x4 accR[4][2], accZ[4][2], accNI[4][2], accNH[4][2];
    #pragma unroll
    for (int i = 0; i < 4; ++i)
        #pragma unroll
        for (int j = 0; j < 2; ++j) {
            accR[i][j] = (f32x4){0.f, 0.f, 0.f, 0.f};
            accZ[i][j] = accR[i][j];
            accNI[i][j] = accR[i][j];
            accNH[i][j] = accR[i][j];
        }

// stage K-step S (0..31) into buffer B. Source select is wave-uniform.
#define GSTAGE(S, B)                                                     \
    {                                                                    \
        const unsigned short* Asrc_ = ((S) < 16) ? prop_bf : emb_bf;     \
        const unsigned short* Bn_   = ((S) < 16) ? Bnit : Bnht;          \
        const int kk_ = ((S) & 15) * GBK;                                \
        const int k0_ = (S) * GBK;                                       \
        glds16(Asrc_ + aOff0 + kk_, &As[B][tid * 8]);                    \
        glds16(Asrc_ + aOff1 + kk_, &As[B][(256 + tid) * 8]);            \
        glds16(Brt + bOffRZ + k0_, &Brs[B][tid * 8]);                    \
        glds16(Bzt + bOffRZ + k0_, &Bzs[B][tid * 8]);                    \
        glds16(Bn_ + bOffN + kk_, &Bns[B][tid * 8]);                     \
    }

// compute one K-step from buffer B; n-gate accumulator chosen at compile time
#define GCOMPUTE(ACCN, B)                                                                            \
    {                                                                                                \
        bf16x8 a[4];                                                                                 \
        _Pragma("unroll")                                                                            \
        for (int i = 0; i < 4; ++i)                                                                  \
            a[i] = *(const bf16x8*)&As[B][(wm + i * 16 + r) * GBK + q * 8];                          \
        _Pragma("unroll")                                                                            \
        for (int j = 0; j < 2; ++j) {                                                                \
            bf16x8 br = *(const bf16x8*)&Brs[B][(wn + j * 16 + r) * GBK + q * 8];                    \
            bf16x8 bz = *(const bf16x8*)&Bzs[B][(wn + j * 16 + r) * GBK + q * 8];                    \
            bf16x8 bn = *(const bf16x8*)&Bns[B][(wn + j * 16 + r) * GBK + q * 8];                    \
            _Pragma("unroll")                                                                        \
            for (int i = 0; i < 4; ++i) {                                                            \
                accR[i][j] = __builtin_amdgcn_mfma_f32_16x16x32_bf16(a[i], br, accR[i][j], 0, 0, 0); \
                accZ[i][j] = __builtin_amdgcn_mfma_f32_16x16x32_bf16(a[i], bz, accZ[i][j], 0, 0, 0); \
                ACCN[i][j] = __builtin_amdgcn_mfma_f32_16x16x32_bf16(a[i], bn, ACCN[i][j], 0, 0, 0); \
            }                                                                                        \
        }                                                                                            \
    }

    GSTAGE(0, 0);
    __syncthreads();                             // tile 0 landed
    int cur = 0;

    for (int s = 0; s < 16; ++s) {               // P-half: n-gate -> accNI
        GSTAGE(s + 1, cur ^ 1);                  // issue-early (s=15 stages step 16 = H-half)
        GCOMPUTE(accNI, cur);
        __syncthreads();
        cur ^= 1;
    }
    for (int s = 16; s < 32; ++s) {              // H-half: n-gate -> accNH
        if (s < 31) GSTAGE(s + 1, cur ^ 1);
        GCOMPUTE(accNH, cur);
        __syncthreads();
        cur ^= 1;
    }
#undef GSTAGE
#undef GCOMPUTE

    #pragma unroll
    for (int j = 0; j < 2; ++j) {
        const int col = colBase + wn + j * 16 + r;
        const float vbir = bir[col], vbiz = biz[col], vbin = bin[col], vbhn = bhn[col];
        #pragma unroll
        for (int i = 0; i < 4; ++i) {
            #pragma unroll
            for (int reg = 0; reg < 4; ++reg) {
                const int row = rowBase + wm + i * 16 + q * 4 + reg;
                if (row >= N) continue;
                float rg = sigmoidf_(accR[i][j][reg] + vbir);
                float zg = sigmoidf_(accZ[i][j][reg] + vbiz);
                float ng = tanhf(accNI[i][j][reg] + vbin + rg * (accNH[i][j][reg] + vbhn));
                float h = emb_f32[(size_t)row * H + col];
                out[(size_t)row * H + col] = (1.0f - zg) * ng + zg * h;
            }
        }
    }
}

extern "C" void kernel_launch(void* const* d_in, const int* in_sizes, int n_in,
                              void* d_out, int out_size, void* d_ws, size_t ws_size,
                              hipStream_t stream) {
    const float* emb     = (const float*)d_in[0];
    const int*   src_idx = (const int*)d_in[1];
    const int*   dst_idx = (const int*)d_in[2];
    const int*   etype   = (const int*)d_in[3];
    const float* W_edge  = (const float*)d_in[6];
    const float* b_edge  = (const float*)d_in[7];
    const float* Wir = (const float*)d_in[8];
    const float* Wiz = (const float*)d_in[9];
    const float* Win = (const float*)d_in[10];
    const float* bir = (const float*)d_in[11];
    const float* biz = (const float*)d_in[12];
    const float* bin = (const float*)d_in[13];
    const float* Whr = (const float*)d_in[14];
    const float* Whz = (const float*)d_in[15];
    const float* Whn = (const float*)d_in[16];
    const float* bhn = (const float*)d_in[17];

    const int E = in_sizes[1];
    const int N = in_sizes[0] / H;
    const int NH = N * H;

    char* ws = (char*)d_ws;
    float*          proposed = (float*)ws;                       ws += (size_t)NH * 4;
    unsigned short* prop_bf  = (unsigned short*)ws;              ws += (size_t)NH * 2;
    unsigned short* emb_bf   = (unsigned short*)ws;              ws += (size_t)NH * 2;
    unsigned short* Brt      = (unsigned short*)ws;              ws += 512 * 1024 * 2;
    unsigned short* Bzt      = (unsigned short*)ws;              ws += 512 * 1024 * 2;
    unsigned short* Bnit     = (unsigned short*)ws;              ws += 512 * 512 * 2;
    unsigned short* Bnht     = (unsigned short*)ws;              ws += 512 * 512 * 2;
    unsigned short* WeT      = (unsigned short*)ws;              ws += 3072 * 512 * 2;
    int*            meta     = (int*)ws;                         ws += 32 * 4;
    int*            perm     = (int*)ws;
    const int maxRowTiles = (E + EBM - 1) / EBM + NT;

    hipMemsetAsync(proposed, 0, (size_t)NH * 4, stream);
    hipMemsetAsync(meta, 0, 32 * 4, stream);
    hipMemsetAsync(perm, 0xFF, (size_t)maxRowTiles * EBM * 4, stream);

    const int n4 = NH / 4;
    conv_bf16_kernel<<<(n4 + 255) / 256, 256, 0, stream>>>(emb, emb_bf, n4);
    conv_gru_w_kernel<<<(512 * 1024 + 255) / 256, 256, 0, stream>>>(
        Wir, Wiz, Win, Whr, Whz, Whn, Brt, Bzt, Bnit, Bnht);
    conv_edge_w_kernel<<<(3072 * 512 + 255) / 256, 256, 0, stream>>>(W_edge, WeT);

    hist_kernel<<<(E + 255) / 256, 256, 0, stream>>>(etype, E, meta);
    prefix_kernel<<<1, 64, 0, stream>>>(meta);
    scatter_perm_kernel<<<(E + 255) / 256, 256, 0, stream>>>(etype, E, meta, perm);

    dim3 egrid(H / EBN, maxRowTiles);
    edge_msg_mfma<<<egrid, 256, 0, stream>>>(emb_bf, src_idx, dst_idx, b_edge, WeT,
                                             meta, perm, proposed);

    conv_bf16_kernel<<<(n4 + 255) / 256, 256, 0, stream>>>(proposed, prop_bf, n4);

    dim3 ggrid(H / GBN, (N + GBM - 1) / GBM);
    gru_mfma<<<ggrid, 256, 0, stream>>>(prop_bf, emb_bf, emb, Brt, Bzt, Bnit, Bnht,
                                        bir, biz, bin, bhn, (float*)d_out, N);
}